// Round 7
// baseline (276.347 us; speedup 1.0000x reference)
//
#include <hip/hip_runtime.h>

// h = x(65536x512) @ W^T(512x256) + bias_lin ; GroupNorm(8 groups of 32)
// ; min over 256 channels -> m[b] ; out[c*B+b] = m[b] + bias[c]
//
// R7 design (theory: all prior kernels were ONE lockstep barrier-group per
// CU with LDS-staged X -> per-tile phases serialize; 6 null interventions).
// X-STATIONARY: each of 8 waves holds its 32 rows of X in registers
// (2 rt x 16 kkg x short8 = 128 VGPR), loaded from global ONCE. W (packed
// bf16 fragments) streams through LDS in two 128KB halves, staged once per
// block. The compute loop has NO barriers, NO global loads, NO LDS writes:
// ds_read(W) + MFMA + in-lane GroupNorm (channels per-lane in D; stats =
// 7 adds + shfl_xor(16,32)) + running-min in registers. Waves drift freely
// -> HBM/LDS/VALU/MFMA overlap across 8 independent streams.
// Barriers: ~5 total (W stagings + final min publish).
#define B_ROWS 65536
#define K_DIM  512
#define N_DIM  256
#define EPS    1e-5f
#define NBLK   256
#define RPB    256                     // rows per block (32 per wave)

using short8  = __attribute__((ext_vector_type(8))) short;
using floatx4 = __attribute__((ext_vector_type(4))) float;
using int4v   = __attribute__((ext_vector_type(4))) int;

// LDS-only barrier: does NOT drain vmcnt.
#define LBAR() do {                                          \
    __builtin_amdgcn_sched_barrier(0);                       \
    asm volatile("s_waitcnt lgkmcnt(0)" ::: "memory");       \
    __builtin_amdgcn_s_barrier();                            \
    __builtin_amdgcn_sched_barrier(0);                       \
} while (0)

__device__ __forceinline__ unsigned short f2bf(float f) {
    unsigned u = __builtin_bit_cast(unsigned, f);
    u += 0x7FFFu + ((u >> 16) & 1u);     // RNE
    return (unsigned short)(u >> 16);
}

// Pack W (256x512 fp32) into bf16 MFMA fragment order (A/B layouts symmetric
// for 16x16x32):
// P[((nt*16 + kkg)*64 + lane)*8 + j] = bf16(W[nt*16 + (lane&15)][kkg*32 + (lane>>4)*8 + j])
__global__ __launch_bounds__(64) void pack_w(const float* __restrict__ W,
                                             unsigned short* __restrict__ P) {
    int b    = blockIdx.x;           // 0..255
    int nt   = b >> 4, kk = b & 15;
    int lane = threadIdx.x;
    int l15  = lane & 15, quad = lane >> 4;
    const float* src = W + (size_t)(nt * 16 + l15) * K_DIM + kk * 32 + quad * 8;
    short8 v;
#pragma unroll
    for (int j = 0; j < 8; ++j) v[j] = (short)f2bf(src[j]);
    *(short8*)(P + ((size_t)(nt * 16 + kk) * 64 + lane) * 8) = v;
}

__global__ __launch_bounds__(512, 2) void fused_xstat(
    const float* __restrict__ X, const unsigned short* __restrict__ P,
    const float* __restrict__ bias_lin, const float* __restrict__ wgn,
    const float* __restrict__ bgn, const float* __restrict__ bias,
    float* __restrict__ out)
{
    __shared__ unsigned short Wsh[8 * 16 * 64 * 8];   // 65536 shorts = 128 KB (one W half)
    __shared__ float par_sh[3 * N_DIM];               // bias_lin | wgn | bgn (3 KB)
    __shared__ float m_sh[RPB];                       // per-row min (1 KB)

    const int tid  = threadIdx.x;
    const int wave = tid >> 6;            // 0..7; owns rows [wave*32, wave*32+32) of the block
    const int lane = tid & 63;
    const int l15  = lane & 15, quad = lane >> 4;

    const size_t row_base = (size_t)blockIdx.x * RPB;

    // ---- stage per-channel params into LDS (once) ----
    if (tid < N_DIM) {
        par_sh[tid]             = bias_lin[tid];
        par_sh[N_DIM + tid]     = wgn[tid];
        par_sh[2 * N_DIM + tid] = bgn[tid];
    }

    // ---- stage W half 0 into LDS (128 KB; 16 x int4 per thread) ----
    const int4v* Pv = (const int4v*)P;    // 16384 int4 units total; half = 8192
    int4v*       Wv = (int4v*)Wsh;
#pragma unroll
    for (int i = 0; i < 16; ++i)
        Wv[i * 512 + tid] = Pv[i * 512 + tid];

    // ---- load this wave's 32 X rows into registers (ONCE), convert to bf16
    //      fragments: xf[rt][kkg][j] = bf16(X[row_base+wave*32+rt*16+l15]
    //                                       [kkg*32 + quad*8 + j]) ----
    short8 xf[2][16];
#pragma unroll
    for (int rt = 0; rt < 2; ++rt) {
        const float* xrow = X + (row_base + wave * 32 + rt * 16 + l15) * K_DIM + quad * 8;
#pragma unroll
        for (int kkg = 0; kkg < 16; ++kkg) {
            float4 lo = *(const float4*)(xrow + kkg * 32);
            float4 hi = *(const float4*)(xrow + kkg * 32 + 4);
            short8 v;
            v[0] = (short)f2bf(lo.x); v[1] = (short)f2bf(lo.y);
            v[2] = (short)f2bf(lo.z); v[3] = (short)f2bf(lo.w);
            v[4] = (short)f2bf(hi.x); v[5] = (short)f2bf(hi.y);
            v[6] = (short)f2bf(hi.z); v[7] = (short)f2bf(hi.w);
            xf[rt][kkg] = v;
        }
    }
    LBAR();   // W half 0 + params visible; X loads unaffected (already consumed)

    float rmin[2] = { 1e30f, 1e30f };

    // ---- process channel halves: h=0 -> ch 0..127, h=1 -> ch 128..255 ----
#pragma unroll
    for (int h = 0; h < 2; ++h) {
        if (h == 1) {
            LBAR();   // all waves done READING Wsh (ds_reads drained per-wave)
#pragma unroll
            for (int i = 0; i < 16; ++i)
                Wv[i * 512 + tid] = Pv[8192 + i * 512 + tid];
            LBAR();   // W half 1 visible
        }

#pragma unroll
        for (int g4 = 0; g4 < 4; ++g4) {          // GN group within half (32 ch)
            const int gbase = h * 128 + g4 * 32;
            // per-lane channel params: ch = gbase + ntp*16 + quad*4 + r
            float bl_[2][4], wg_[2][4], bg_[2][4];
#pragma unroll
            for (int ntp = 0; ntp < 2; ++ntp)
#pragma unroll
                for (int r = 0; r < 4; ++r) {
                    int ch = gbase + ntp * 16 + quad * 4 + r;
                    bl_[ntp][r] = par_sh[ch];
                    wg_[ntp][r] = par_sh[N_DIM + ch];
                    bg_[ntp][r] = par_sh[2 * N_DIM + ch];
                }

            floatx4 acc[2][2];                     // [ntp][rt]
#pragma unroll
            for (int ntp = 0; ntp < 2; ++ntp)
#pragma unroll
                for (int rt = 0; rt < 2; ++rt)
#pragma unroll
                    for (int r = 0; r < 4; ++r)
                        acc[ntp][rt][r] = bl_[ntp][r];

#pragma unroll
            for (int ntp = 0; ntp < 2; ++ntp) {
                const int ntl = g4 * 2 + ntp;      // local nt within half
#pragma unroll
                for (int kkg = 0; kkg < 16; ++kkg) {
                    short8 wv = *(const short8*)&Wsh[(((size_t)ntl * 16 + kkg) * 64 + lane) * 8];
                    acc[ntp][0] = __builtin_amdgcn_mfma_f32_16x16x32_bf16(wv, xf[0][kkg], acc[ntp][0], 0, 0, 0);
                    acc[ntp][1] = __builtin_amdgcn_mfma_f32_16x16x32_bf16(wv, xf[1][kkg], acc[ntp][1], 0, 0, 0);
                }
            }

            // GroupNorm over this 32-ch group, per row rt*16+l15, then min
#pragma unroll
            for (int rt = 0; rt < 2; ++rt) {
                float s = 0.f, ss = 0.f;
#pragma unroll
                for (int ntp = 0; ntp < 2; ++ntp)
#pragma unroll
                    for (int r = 0; r < 4; ++r) {
                        float v = acc[ntp][rt][r];
                        s += v; ss = fmaf(v, v, ss);
                    }
                s  += __shfl_xor(s, 16);  s  += __shfl_xor(s, 32);
                ss += __shfl_xor(ss, 16); ss += __shfl_xor(ss, 32);
                float mean = s * (1.0f / 32.0f);
                float var  = ss * (1.0f / 32.0f) - mean * mean;
                float inv  = rsqrtf(var + EPS);
                float mi   = mean * inv;
                float mn   = rmin[rt];
#pragma unroll
                for (int ntp = 0; ntp < 2; ++ntp)
#pragma unroll
                    for (int r = 0; r < 4; ++r) {
                        float g = fmaf(fmaf(acc[ntp][rt][r], inv, -mi), wg_[ntp][r], bg_[ntp][r]);
                        mn = fminf(mn, g);
                    }
                rmin[rt] = mn;
            }
        }
    }

    // ---- combine min across quads (lane's 64 ch -> row's 256 ch), publish ----
#pragma unroll
    for (int rt = 0; rt < 2; ++rt) {
        float mn = rmin[rt];
        mn = fminf(mn, __shfl_xor(mn, 16));
        mn = fminf(mn, __shfl_xor(mn, 32));
        if (quad == 0) m_sh[wave * 32 + rt * 16 + l15] = mn;
    }
    LBAR();

    // ---- bulk write: thread -> channel c = tid>>1, half q = tid&1;
    //      contiguous 512 B per thread, 1 KB per channel per block ----
    {
        int c = tid >> 1;
        int q = tid & 1;
        float bc = bias[c];
        float* dst = out + (size_t)c * B_ROWS + row_base + q * 128;
#pragma unroll
        for (int i = 0; i < 32; ++i) {
            float4 mv = *(const float4*)&m_sh[q * 128 + i * 4];
            float4 o;
            o.x = mv.x + bc; o.y = mv.y + bc; o.z = mv.z + bc; o.w = mv.w + bc;
            *(float4*)(dst + i * 4) = o;
        }
    }
}

extern "C" void kernel_launch(void* const* d_in, const int* in_sizes, int n_in,
                              void* d_out, int out_size, void* d_ws, size_t ws_size,
                              hipStream_t stream) {
    const float* x    = (const float*)d_in[0];
    const float* w    = (const float*)d_in[1];
    const float* bl   = (const float*)d_in[2];
    const float* wg   = (const float*)d_in[3];
    const float* bg   = (const float*)d_in[4];
    const float* bias = (const float*)d_in[5];

    unsigned short* P = (unsigned short*)d_ws;     // 256 KB packed bf16 W
    float* out = (float*)d_out;

    hipLaunchKernelGGL(pack_w, dim3(256), dim3(64), 0, stream, w, P);
    hipLaunchKernelGGL(fused_xstat, dim3(NBLK), dim3(512), 0, stream,
                       x, P, bl, wg, bg, bias, out);
}

// Round 9
// 229.740 us; speedup vs baseline: 1.2029x; 1.2029x over previous
//
#include <hip/hip_runtime.h>

// h = x(65536x512) @ W^T(512x256) + bias_lin ; GroupNorm(8 groups of 32)
// ; min over 256 channels -> m[b] ; out[c*B+b] = m[b] + bias[c]
//
// R8: two-kernel split (diagnostic + likely win). The fused output is a
// rank-1 broadcast of m[65536] (256 KB), so the 64-MB write does not need
// to live inside the compute kernel.
//   K1 fused_gemm_min: R5's exact compute structure (1024 thr, 16 waves,
//      W-stationary, double-buffered LDS X, vmcnt-preserving LBARs), but
//      writes only m[] (256 KB). Pure read-side stream -> clean FETCH.
//   K2 bcast_out: out4[j] = m4[j & 16383] + bias[j >> 14]; 2048 blk x 256
//      thr, channel constant per block, fully coalesced. Pure write-side.
// (R8 bench was an infra failure — resubmitted unchanged.)
#define B_ROWS 65536
#define K_DIM  512
#define N_DIM  256
#define EPS    1e-5f
#define MTILE  32
#define NBLK   256
#define TILES  (B_ROWS / MTILE)
#define STRIDE 520      // 512 + 8 pad (bf16)

using short8  = __attribute__((ext_vector_type(8))) short;
using floatx4 = __attribute__((ext_vector_type(4))) float;

// LDS-only barrier: does NOT drain vmcnt (prefetch loads stay in flight).
#define LBAR() do {                                          \
    __builtin_amdgcn_sched_barrier(0);                       \
    asm volatile("s_waitcnt lgkmcnt(0)" ::: "memory");       \
    __builtin_amdgcn_s_barrier();                            \
    __builtin_amdgcn_sched_barrier(0);                       \
} while (0)

__device__ __forceinline__ unsigned short f2bf(float f) {
    unsigned u = __builtin_bit_cast(unsigned, f);
    u += 0x7FFFu + ((u >> 16) & 1u);     // RNE
    return (unsigned short)(u >> 16);
}

// Pack W (256x512 fp32) into bf16 MFMA fragment order (A/B layouts symmetric
// for 16x16x32):
// P[((nt*16 + kkg)*64 + lane)*8 + j] = bf16(W[nt*16 + (lane&15)][kkg*32 + (lane>>4)*8 + j])
__global__ __launch_bounds__(64) void pack_w(const float* __restrict__ W,
                                             unsigned short* __restrict__ P) {
    int b    = blockIdx.x;           // 0..255
    int nt   = b >> 4, kk = b & 15;
    int lane = threadIdx.x;
    int l15  = lane & 15, quad = lane >> 4;
    const float* src = W + (size_t)(nt * 16 + l15) * K_DIM + kk * 32 + quad * 8;
    short8 v;
#pragma unroll
    for (int j = 0; j < 8; ++j) v[j] = (short)f2bf(src[j]);
    *(short8*)(P + ((size_t)(nt * 16 + kk) * 64 + lane) * 8) = v;
}

__global__ __launch_bounds__(1024) void fused_gemm_min(
    const float* __restrict__ X, const unsigned short* __restrict__ P,
    const float* __restrict__ bias_lin, const float* __restrict__ wgn,
    const float* __restrict__ bgn, float* __restrict__ m_out)
{
    __shared__ unsigned short Ash[2][MTILE * STRIDE];   // 2 x 33280 B
    __shared__ float smS[16][32];                        // per-wave partial sums
    __shared__ float smSS[16][32];
    __shared__ float smin[16][32];                       // per-wave 16-ch min

    const int tid  = threadIdx.x;
    const int wave = tid >> 6;            // 0..15; owns channels [16*wave, 16*wave+16)
    const int lane = tid & 63;
    const int l15  = lane & 15, quad = lane >> 4;

    // ---- this wave's W fragments: 16 short8 (nt == wave) ----
    short8 bfr[16];
#pragma unroll
    for (int kkg = 0; kkg < 16; ++kkg)
        bfr[kkg] = *(const short8*)(P + (((size_t)wave * 16 + kkg) * 64 + lane) * 8);

    // per-lane channel params: ch = wave*16 + quad*4 + r
    float blr[4], wgr[4], bgr[4];
#pragma unroll
    for (int r = 0; r < 4; ++r) {
        int c = wave * 16 + quad * 4 + r;
        blr[r] = bias_lin[c]; wgr[r] = wgn[c]; bgr[r] = bgn[c];
    }

    // staging geometry: tile = 32 rows x 128 float4; thread covers rows
    // r0..r0+3 (r0 = (tid>>7)*4) at fp32 cols [c4, c4+4)
    const int r0 = (tid >> 7) * 4;
    const int c4 = (tid & 127) * 4;

    int t = blockIdx.x;

    // prologue: load + stage tile t into buf0, issue prefetch of t+NBLK
    float4 xq[4];
#pragma unroll
    for (int p = 0; p < 4; ++p)
        xq[p] = *(const float4*)(X + (size_t)(t * MTILE + r0 + p) * K_DIM + c4);
#pragma unroll
    for (int p = 0; p < 4; ++p) {
        ushort4 h;
        h.x = f2bf(xq[p].x); h.y = f2bf(xq[p].y);
        h.z = f2bf(xq[p].z); h.w = f2bf(xq[p].w);
        *(ushort4*)(&Ash[0][(r0 + p) * STRIDE + c4]) = h;
    }
    if (t + NBLK < TILES) {
#pragma unroll
        for (int p = 0; p < 4; ++p)
            xq[p] = *(const float4*)(X + (size_t)((t + NBLK) * MTILE + r0 + p) * K_DIM + c4);
    }
    LBAR();

    int cur = 0;
    for (; t < TILES; t += NBLK) {
        // ---- stage NEXT tile into the other buffer, prefetch t+2*NBLK ----
        if (t + NBLK < TILES) {
#pragma unroll
            for (int p = 0; p < 4; ++p) {
                ushort4 h;
                h.x = f2bf(xq[p].x); h.y = f2bf(xq[p].y);
                h.z = f2bf(xq[p].z); h.w = f2bf(xq[p].w);
                *(ushort4*)(&Ash[cur ^ 1][(r0 + p) * STRIDE + c4]) = h;
            }
            if (t + 2 * NBLK < TILES) {
#pragma unroll
                for (int p = 0; p < 4; ++p)
                    xq[p] = *(const float4*)(X + (size_t)((t + 2 * NBLK) * MTILE + r0 + p) * K_DIM + c4);
            }
        }

        // ---- K-loop on current buffer: D[ch16][row32] = W·X^T, bias in C-init ----
        floatx4 acc[2];
#pragma unroll
        for (int rt = 0; rt < 2; ++rt)
#pragma unroll
            for (int r = 0; r < 4; ++r) acc[rt][r] = blr[r];
#pragma unroll
        for (int kk = 0; kk < 16; ++kk) {
            short8 a0 = *(const short8*)&Ash[cur][(l15)      * STRIDE + kk * 32 + quad * 8];
            short8 a1 = *(const short8*)&Ash[cur][(16 + l15) * STRIDE + kk * 32 + quad * 8];
            acc[0] = __builtin_amdgcn_mfma_f32_16x16x32_bf16(bfr[kk], a0, acc[0], 0, 0, 0);
            acc[1] = __builtin_amdgcn_mfma_f32_16x16x32_bf16(bfr[kk], a1, acc[1], 0, 0, 0);
        }

        // ---- GroupNorm stats: in-lane over 4 ch + quad shfl -> wave's 16 ch;
        //      combine with partner wave (wave^1) via LDS ----
        float sreg[2], ssreg[2];
#pragma unroll
        for (int rt = 0; rt < 2; ++rt) {
            float s = 0.f, ss = 0.f;
#pragma unroll
            for (int r = 0; r < 4; ++r) { float v = acc[rt][r]; s += v; ss = fmaf(v, v, ss); }
            s  += __shfl_xor(s, 16);  s  += __shfl_xor(s, 32);
            ss += __shfl_xor(ss, 16); ss += __shfl_xor(ss, 32);
            sreg[rt] = s; ssreg[rt] = ss;
            if (quad == 0) { smS[wave][rt * 16 + l15] = s; smSS[wave][rt * 16 + l15] = ss; }
        }
        LBAR();

#pragma unroll
        for (int rt = 0; rt < 2; ++rt) {
            int row = rt * 16 + l15;
            float st   = sreg[rt]  + smS[wave ^ 1][row];    // 32-ch sums
            float sst  = ssreg[rt] + smSS[wave ^ 1][row];
            float mean = st * (1.0f / 32.0f);
            float var  = sst * (1.0f / 32.0f) - mean * mean;
            float inv  = rsqrtf(var + EPS);
            float mi   = mean * inv;
            float mn   = 1e30f;
#pragma unroll
            for (int r = 0; r < 4; ++r) {
                float g = fmaf(fmaf(acc[rt][r], inv, -mi), wgr[r], bgr[r]);
                mn = fminf(mn, g);
            }
            mn = fminf(mn, __shfl_xor(mn, 16));
            mn = fminf(mn, __shfl_xor(mn, 32));
            if (quad == 0) smin[wave][row] = mn;
        }
        LBAR();

        // ---- final 16-way min + direct m write (128 B per block-iter) ----
        if (tid < MTILE) {
            float m0 = smin[0][tid];
#pragma unroll
            for (int w = 1; w < 16; ++w) m0 = fminf(m0, smin[w][tid]);
            m_out[t * MTILE + tid] = m0;
        }
        cur ^= 1;
        // Ash handoff safety: next iter's staging (buf cur) postdates both
        // LBARs above, which postdate ALL waves' K-loop ds_reads of that
        // buffer (lgkmcnt(0) per wave). smin reads by wave 0 race nothing:
        // next smin write is behind the NEXT iteration's two LBARs.
    }
}

// out4[j] = m4[j & 16383] + bias[j >> 14]; channel constant per block.
__global__ __launch_bounds__(256) void bcast_out(
    const float* __restrict__ m, const float* __restrict__ bias,
    float* __restrict__ out)
{
    const float4* m4  = (const float4*)m;
    float4*       o4  = (float4*)out;
    const int bid = blockIdx.x;          // 0..2047
    const int c   = bid >> 3;            // 8 blocks per channel
    const float bc = bias[c];
    const int base = (bid & 7) * 2048;   // float4 offset within channel
#pragma unroll
    for (int k = 0; k < 8; ++k) {
        int idx = base + k * 256 + threadIdx.x;          // 0..16383
        float4 mv = m4[idx];
        float4 o;
        o.x = mv.x + bc; o.y = mv.y + bc; o.z = mv.z + bc; o.w = mv.w + bc;
        o4[(size_t)c * (B_ROWS / 4) + idx] = o;
    }
}

extern "C" void kernel_launch(void* const* d_in, const int* in_sizes, int n_in,
                              void* d_out, int out_size, void* d_ws, size_t ws_size,
                              hipStream_t stream) {
    const float* x    = (const float*)d_in[0];
    const float* w    = (const float*)d_in[1];
    const float* bl   = (const float*)d_in[2];
    const float* wg   = (const float*)d_in[3];
    const float* bg   = (const float*)d_in[4];
    const float* bias = (const float*)d_in[5];

    unsigned short* P = (unsigned short*)d_ws;                 // 256 KB packed bf16 W
    float* m          = (float*)((char*)d_ws + 262144);        // 256 KB per-row min
    float* out        = (float*)d_out;

    hipLaunchKernelGGL(pack_w, dim3(256), dim3(64), 0, stream, w, P);
    hipLaunchKernelGGL(fused_gemm_min, dim3(NBLK), dim3(1024), 0, stream,
                       x, P, bl, wg, bg, m);
    hipLaunchKernelGGL(bcast_out, dim3(2048), dim3(256), 0, stream, m, bias, out);
}